// Round 5
// baseline (511.066 us; speedup 1.0000x reference)
//
#include <hip/hip_runtime.h>
#include <stdint.h>

#define S 2048
#define E 2048
#define NH 16
#define NG 4
#define HD 128
#define BK 64      // K-step for the async global_load_lds GEMM core

using short8 = __attribute__((ext_vector_type(8))) short;  // 8 bf16 (4 VGPRs)
using f32x4  = __attribute__((ext_vector_type(4))) float;  // 4 fp32 acc

__device__ __forceinline__ unsigned short f2bf(float f){
    union { float f; unsigned int i; } v; v.f = f;
    unsigned int x = v.i;
    unsigned int r = x + 0x7FFFu + ((x >> 16) & 1u);  // round-to-nearest-even
    return (unsigned short)(r >> 16);
}

// ---------------- async (global_load_lds) helpers ----------------
// 16B direct-to-LDS copy. LDS dest must be wave-uniform base + lane*16;
// global source is per-lane (so the swizzle lives on the SOURCE side).
__device__ __forceinline__ void async_cp16(const unsigned short* g, unsigned short* l){
    __builtin_amdgcn_global_load_lds((const __attribute__((address_space(1))) void*)g,
                                     (__attribute__((address_space(3))) void*)l,
                                     16, 0, 0);
}

// Stage a 128 x BK(=64) bf16 tile, linear LDS dest, XOR-swizzled source chunks.
__device__ __forceinline__ void stage_tile_async(const unsigned short* __restrict__ G,
                                                 int ld, int k0,
                                                 unsigned short* lds)
{
    int tid = threadIdx.x;
    #pragma unroll
    for (int c = 0; c < 4; c++) {
        int e  = (c * 256 + tid) * 8;   // dest elem index in tile (0..8191)
        int r  = e >> 6;                // row 0..127
        int cl = (e >> 3) & 7;          // dest 16B chunk 0..7
        int sc = cl ^ (r & 7);          // swizzled source chunk
        async_cp16(G + (size_t)r * ld + k0 + sc * 8, lds + e);
    }
}

// Stage a 128 x 128 bf16 tile (32 KB): 16 chunks/row, XOR-swizzle with row&15.
__device__ __forceinline__ void stage_128x128(const unsigned short* __restrict__ G,
                                              int ld, unsigned short* lds)
{
    int tid = threadIdx.x;
    #pragma unroll
    for (int c = 0; c < 8; c++) {
        int e  = (c * 256 + tid) * 8;   // 0..16383
        int r  = e >> 7;                // row 0..127
        int cl = (e >> 3) & 15;         // dest chunk 0..15
        int sc = cl ^ (r & 15);         // swizzled source chunk
        async_cp16(G + (size_t)r * ld + sc * 8, lds + e);
    }
}

// Stage a 64 x 128 bf16 tile (16 KB).
__device__ __forceinline__ void stage_64x128(const unsigned short* __restrict__ G,
                                             int ld, unsigned short* lds)
{
    int tid = threadIdx.x;
    #pragma unroll
    for (int c = 0; c < 4; c++) {
        int e  = (c * 256 + tid) * 8;   // 0..8191
        int r  = e >> 7;                // row 0..63
        int cl = (e >> 3) & 15;
        int sc = cl ^ (r & 15);
        async_cp16(G + (size_t)r * ld + sc * 8, lds + e);
    }
}

// ---------------- bf16 GEMM core: 128x128 tile, BK=64, LDS double-buffered
__device__ __forceinline__ void gemm_core_async(const unsigned short* __restrict__ A, int lda,
                                                const unsigned short* __restrict__ Bt, int ldb,
                                                int K, f32x4 acc[4][4],
                                                unsigned short* lA, unsigned short* lB) // each [2][128*BK]
{
    int tid = threadIdx.x;
    int wave = tid >> 6, lane = tid & 63;
    int mBase = (wave >> 1) * 64, nBase = (wave & 1) * 64;
    int rowA = lane & 15, qc = lane >> 4;
    int nt = K / BK;
    stage_tile_async(A,  lda, 0, lA);
    stage_tile_async(Bt, ldb, 0, lB);
    __syncthreads();
    int cur = 0;
    for (int t = 0; t < nt; ++t) {
        if (t + 1 < nt) {   // prefetch next K-step into the other buffer
            stage_tile_async(A,  lda, (t + 1) * BK, lA + (cur ^ 1) * (128 * BK));
            stage_tile_async(Bt, ldb, (t + 1) * BK, lB + (cur ^ 1) * (128 * BK));
        }
        const unsigned short* cA = lA + cur * (128 * BK);
        const unsigned short* cB = lB + cur * (128 * BK);
        #pragma unroll
        for (int s = 0; s < 2; s++) {
            short8 af[4], bfr[4];
            #pragma unroll
            for (int i = 0; i < 4; i++) {
                int r  = mBase + i * 16 + rowA;
                int ch = (s * 4 + qc) ^ (r & 7);
                af[i] = *(const short8*)&cA[r * BK + ch * 8];
            }
            #pragma unroll
            for (int j = 0; j < 4; j++) {
                int r  = nBase + j * 16 + rowA;
                int ch = (s * 4 + qc) ^ (r & 7);
                bfr[j] = *(const short8*)&cB[r * BK + ch * 8];
            }
            #pragma unroll
            for (int i = 0; i < 4; i++)
                #pragma unroll
                for (int j = 0; j < 4; j++)
                    acc[i][j] = __builtin_amdgcn_mfma_f32_16x16x32_bf16(af[i], bfr[j], acc[i][j], 0, 0, 0);
        }
        __syncthreads();   // prefetch landed + all waves done with cur
        cur ^= 1;
    }
}

// C/D layout: col = lane&15, row = (lane>>4)*4 + reg.
template<bool BF16OUT>
__device__ __forceinline__ void epilogue(f32x4 acc[4][4], void* Cv, int ldc,
                                         int row0, int col0, float scale)
{
    int tid = threadIdx.x, wave = tid >> 6, lane = tid & 63;
    int mBase = (wave >> 1) * 64, nBase = (wave & 1) * 64;
    int col = lane & 15, quad = lane >> 4;
    #pragma unroll
    for (int i = 0; i < 4; i++)
        #pragma unroll
        for (int j = 0; j < 4; j++)
            #pragma unroll
            for (int r = 0; r < 4; r++) {
                int gr = row0 + mBase + i * 16 + quad * 4 + r;
                int gc = col0 + nBase + j * 16 + col;
                float v = acc[i][j][r] * scale;
                if (BF16OUT) ((unsigned short*)Cv)[(size_t)gr * ldc + gc] = f2bf(v);
                else         ((float*)Cv)[(size_t)gr * ldc + gc] = v;
            }
}

template<bool BF16OUT>
__global__ __launch_bounds__(256) void gemm_mfma_as(const unsigned short* __restrict__ A, int lda,
                                                    const unsigned short* __restrict__ Bt, int ldb,
                                                    void* __restrict__ C, int ldc, int K)
{
    __shared__ unsigned short lA[2 * 128 * BK];
    __shared__ unsigned short lB[2 * 128 * BK];
    int row0 = blockIdx.y * 128, col0 = blockIdx.x * 128;
    f32x4 acc[4][4] = {};
    gemm_core_async(A + (size_t)row0 * lda, lda, Bt + (size_t)col0 * ldb, ldb, K, acc, lA, lB);
    epilogue<BF16OUT>(acc, C, ldc, row0, col0, 1.0f);
}

// ---------------- fused QKV GEMM: epilogue applies RoPE (Q,K) / transpose (V)
// and writes bf16 directly. C tile staged through LDS (reuses the GEMM bufs).
__global__ __launch_bounds__(256) void qkv_gemm_fused(const unsigned short* __restrict__ A,  // xbf [S][E]
                                                      const unsigned short* __restrict__ Bt, // Wqkvt [3072][E]
                                                      const float* __restrict__ cosp,
                                                      const float* __restrict__ sinp,
                                                      unsigned short* __restrict__ Qbf,
                                                      unsigned short* __restrict__ Kbf,
                                                      unsigned short* __restrict__ Vt)
{
    __shared__ unsigned short smem[4 * 128 * BK];   // 64 KB: lA(32K) | lB(32K), then f32 C-tile
    unsigned short* lA = smem;
    unsigned short* lB = smem + 2 * 128 * BK;
    int row0 = blockIdx.y * 128, col0 = blockIdx.x * 128;
    f32x4 acc[4][4] = {};
    gemm_core_async(A + (size_t)row0 * E, E, Bt + (size_t)col0 * E, E, E, acc, lA, lB);

    // acc -> LDS f32 C tile [128][128] (core's final barrier: lA/lB fully consumed)
    float* ct = (float*)smem;
    int tid = threadIdx.x, wave = tid >> 6, lane = tid & 63;
    int mBase = (wave >> 1) * 64, nBase = (wave & 1) * 64;
    int colI = lane & 15, quad = lane >> 4;
    #pragma unroll
    for (int i = 0; i < 4; i++)
        #pragma unroll
        for (int j = 0; j < 4; j++)
            #pragma unroll
            for (int r = 0; r < 4; r++)
                ct[(mBase + i * 16 + quad * 4 + r) * 128 + (nBase + j * 16 + colI)] = acc[i][j][r];
    __syncthreads();

    int sect = blockIdx.x;   // 0..15 Q heads, 16..19 K heads, 20..23 V heads
    if (sect < 20) {
        // ---- RoPE path (Q: scale folded; K: scale 1) ----
        bool isQ = (sect < 16);
        unsigned short* out = isQ ? Qbf : Kbf;
        int outLd = isQ ? (NH * HD) : (NG * HD);
        int hoff  = isQ ? sect * HD : (sect - 16) * HD;
        float SC  = isQ ? 0.08838834764831845f : 1.0f;
        #pragma unroll
        for (int k = 0; k < 8; k++) {
            int chunk = k * 256 + tid;       // 0..2047
            int row = chunk >> 4;            // 0..127
            int d0  = (chunk & 15) * 8;      // 8-elem chunk start
            int srow = row0 + row;
            unsigned int w[4];
            #pragma unroll
            for (int e2 = 0; e2 < 4; e2++) {
                unsigned short h2[2];
                #pragma unroll
                for (int u = 0; u < 2; u++) {
                    int d = d0 + e2 * 2 + u;
                    float xv = ct[row * 128 + d];
                    float c  = cosp[(size_t)srow * HD + d];
                    float sn = sinp[(size_t)srow * HD + d];
                    float partner = (d < 64) ? -ct[row * 128 + d + 64]
                                             :  ct[row * 128 + d - 64];
                    h2[u] = f2bf((xv * c + partner * sn) * SC);
                }
                w[e2] = (unsigned int)h2[0] | ((unsigned int)h2[1] << 16);
            }
            *(uint4*)&out[(size_t)srow * outLd + hoff + d0] = make_uint4(w[0], w[1], w[2], w[3]);
        }
    } else {
        // ---- V path: transpose to Vt[d][s] bf16 ----
        int dg0 = (sect - 20) * 128;
        int d   = tid >> 1;                  // 0..127
        int sc0 = (tid & 1) * 64;            // half of the 128 s-values
        #pragma unroll
        for (int k = 0; k < 8; k++) {
            int s0 = sc0 + k * 8;
            unsigned int w[4];
            #pragma unroll
            for (int e2 = 0; e2 < 4; e2++) {
                unsigned short a0 = f2bf(ct[(s0 + e2 * 2) * 128 + d]);
                unsigned short a1 = f2bf(ct[(s0 + e2 * 2 + 1) * 128 + d]);
                w[e2] = (unsigned int)a0 | ((unsigned int)a1 << 16);
            }
            *(uint4*)&Vt[(size_t)(dg0 + d) * S + row0 + s0] = make_uint4(w[0], w[1], w[2], w[3]);
        }
    }
}

// ---------------- single-pass flash attention ----------------
// Each WAVE owns complete rows (16 q-rows x all 128 cols) -> softmax stats
// are wave-local. Online rescale of O; emits per-row (m, 1/l) for p_write.
__device__ __forceinline__ float rmax16(float v){
    v = fmaxf(v, __shfl_xor(v, 1)); v = fmaxf(v, __shfl_xor(v, 2));
    v = fmaxf(v, __shfl_xor(v, 4)); v = fmaxf(v, __shfl_xor(v, 8));
    return v;
}
__device__ __forceinline__ float rsum16(float v){
    v += __shfl_xor(v, 1); v += __shfl_xor(v, 2);
    v += __shfl_xor(v, 4); v += __shfl_xor(v, 8);
    return v;
}

// QK^T: 16 rows (this wave) x 128 cols from Q-frags (regs) + K tile in LDS.
__device__ __forceinline__ void qk_compute(const short8 qf[4], const unsigned short* lK,
                                           int rowA, int quad, f32x4 sacc[8])
{
    #pragma unroll
    for (int j = 0; j < 8; j++)
        #pragma unroll
        for (int r = 0; r < 4; r++) sacc[j][r] = 0.f;
    __builtin_amdgcn_s_setprio(1);
    #pragma unroll
    for (int ks = 0; ks < 4; ks++) {
        int ch = (ks * 4 + quad) ^ rowA;   // (j*16+rowA)&15 == rowA
        #pragma unroll
        for (int j = 0; j < 8; j++) {
            short8 kf = *(const short8*)&lK[(j * 16 + rowA) * 128 + ch * 8];
            sacc[j] = __builtin_amdgcn_mfma_f32_16x16x32_bf16(qf[ks], kf, sacc[j], 0, 0, 0);
        }
    }
    __builtin_amdgcn_s_setprio(0);
}

__global__ __launch_bounds__(256, 2) void attn_flash(const unsigned short* __restrict__ Q,
                                                     const unsigned short* __restrict__ Kb,
                                                     const unsigned short* __restrict__ Vt,
                                                     unsigned short* __restrict__ Obf,
                                                     float* __restrict__ Mrow,
                                                     float* __restrict__ Li)
{
    __shared__ unsigned short lK[128 * 128];   // K tile (front 16KB doubles as Q tile)
    __shared__ unsigned short lV[128 * 128];   // V^T tile
    __shared__ unsigned short lP[64 * 128];    // packed bf16 unnormalized P tile
    int h = blockIdx.x, qt = (gridDim.y - 1) - blockIdx.y, g = h >> 2; // heavy blocks first
    int jtm = qt >> 1;                 // diag (last) K/V tile index
    int rbase = (qt & 1) * 64;         // our rows' offset within the 128-row diag tile
    int tid = threadIdx.x, wave = tid >> 6, lane = tid & 63;
    int rowA = lane & 15, quad = lane >> 4;

    // Q (64x128, pre-scaled by 1/sqrt(HD)) -> LDS -> registers
    stage_64x128(Q + (size_t)(qt * 64) * (NH * HD) + h * HD, NH * HD, lK);
    __syncthreads();
    short8 qf[4];
    #pragma unroll
    for (int ks = 0; ks < 4; ks++) {
        int r = wave * 16 + rowA;
        int ch = (ks * 4 + quad) ^ rowA;   // r&15 == rowA
        qf[ks] = *(const short8*)&lK[r * 128 + ch * 8];
    }

    f32x4 m_, l_;
    #pragma unroll
    for (int r = 0; r < 4; r++) { m_[r] = -1e30f; l_[r] = 0.f; }
    f32x4 oacc[8];
    #pragma unroll
    for (int j = 0; j < 8; j++)
        #pragma unroll
        for (int r = 0; r < 4; r++) oacc[j][r] = 0.f;

    for (int jt = 0; jt <= jtm; ++jt) {
        __syncthreads();   // prev round's lK/lV/lP fully consumed (also guards qf reads)
        stage_128x128(Kb + (size_t)(jt * 128) * (NG * HD) + g * HD, NG * HD, lK);
        stage_128x128(Vt + (size_t)(g * HD) * S + jt * 128, S, lV);
        __syncthreads();   // tiles resident
        f32x4 sacc[8];
        qk_compute(qf, lK, rowA, quad, sacc);
        if (jt == jtm) {
            #pragma unroll
            for (int j = 0; j < 8; j++)
                #pragma unroll
                for (int r = 0; r < 4; r++) {
                    int row = rbase + wave * 16 + quad * 4 + r;
                    int col = j * 16 + rowA;
                    if (col > row) sacc[j][r] = -1e30f;
                }
        }
        // online softmax update + O rescale; sacc becomes p = exp(s - m_new)
        #pragma unroll
        for (int r = 0; r < 4; r++) {
            float tm = sacc[0][r];
            #pragma unroll
            for (int j = 1; j < 8; j++) tm = fmaxf(tm, sacc[j][r]);
            tm = rmax16(tm);
            float mn = fmaxf(m_[r], tm);
            float sc = __expf(m_[r] - mn);
            float es = 0.f;
            #pragma unroll
            for (int j = 0; j < 8; j++) {
                float p = __expf(sacc[j][r] - mn);
                sacc[j][r] = p;
                es += p;
            }
            es = rsum16(es);
            l_[r] = l_[r] * sc + es;
            m_[r] = mn;
            #pragma unroll
            for (int j = 0; j < 8; j++) oacc[j][r] *= sc;
        }
        // pack unnormalized p -> lP (bf16, swizzled)
        #pragma unroll
        for (int j = 0; j < 8; j++)
            #pragma unroll
            for (int r = 0; r < 4; r++) {
                int row = wave * 16 + quad * 4 + r;    // local 0..63
                int col = j * 16 + rowA;
                int ch = col >> 3;
                lP[row * 128 + (((ch ^ (row & 15)) << 3) | (col & 7))] = f2bf(sacc[j][r]);
            }
        __syncthreads();   // lP fully packed
        __builtin_amdgcn_s_setprio(1);
        #pragma unroll
        for (int ks = 0; ks < 4; ks++) {
            int ch = (ks * 4 + quad) ^ rowA;
            short8 pa = *(const short8*)&lP[(wave * 16 + rowA) * 128 + ch * 8];
            #pragma unroll
            for (int j = 0; j < 8; j++) {
                short8 vb = *(const short8*)&lV[(j * 16 + rowA) * 128 + ch * 8];
                oacc[j] = __builtin_amdgcn_mfma_f32_16x16x32_bf16(pa, vb, oacc[j], 0, 0, 0);
            }
        }
        __builtin_amdgcn_s_setprio(0);
    }

    f32x4 linv;
    #pragma unroll
    for (int r = 0; r < 4; r++) linv[r] = 1.0f / l_[r];

    // O rows -> Obf (bf16, head-sliced cols), normalized
    #pragma unroll
    for (int j = 0; j < 8; j++)
        #pragma unroll
        for (int r = 0; r < 4; r++) {
            int row = qt * 64 + wave * 16 + quad * 4 + r;
            int col = h * HD + j * 16 + rowA;
            Obf[(size_t)row * (NH * HD) + col] = f2bf(oacc[j][r] * linv[r]);
        }

    // per-row softmax stats for the P-writer (one lane per row group)
    if (rowA == 0) {
        int grow0 = qt * 64 + wave * 16 + quad * 4;
        #pragma unroll
        for (int r = 0; r < 4; r++) {
            Mrow[(size_t)h * S + grow0 + r] = m_[r];
            Li[(size_t)h * S + grow0 + r]  = linv[r];
        }
    }
}

// ---------------- P-writer: recompute S once, write final P ----------------
__global__ __launch_bounds__(256) void p_write(const unsigned short* __restrict__ Q,
                                               const unsigned short* __restrict__ Kb,
                                               const float* __restrict__ Mrow,
                                               const float* __restrict__ Li,
                                               float* __restrict__ P)
{
    int jt = blockIdx.x, it = blockIdx.y, h = blockIdx.z;
    float* Pt = P + (size_t)h * S * S + (size_t)(it * 128) * S + jt * 128;
    int tid = threadIdx.x;
    if (jt > it) {   // upper triangle: zeros
        #pragma unroll
        for (int q = 0; q < 16; q++) {
            int e4 = q * 256 + tid;          // float4 index 0..4095
            int r  = e4 >> 5;                // 32 float4 per 128-col row
            int c4 = (e4 & 31) * 4;
            *(float4*)(Pt + (size_t)r * S + c4) = make_float4(0.f, 0.f, 0.f, 0.f);
        }
        return;
    }
    __shared__ unsigned short lA[2 * 128 * BK];
    __shared__ unsigned short lB[2 * 128 * BK];
    f32x4 acc[4][4] = {};
    gemm_core_async(Q + (size_t)(it * 128) * (NH * HD) + h * HD, NH * HD,
                    Kb + (size_t)(jt * 128) * (NG * HD) + (h >> 2) * HD, NG * HD,
                    HD, acc, lA, lB);
    // epilogue: exp(s - m) * linv, diag-masked
    int wave = tid >> 6, lane = tid & 63;
    int mBase = (wave >> 1) * 64, nBase = (wave & 1) * 64;
    int col = lane & 15, quad = lane >> 4;
    bool diag = (jt == it);
    #pragma unroll
    for (int i = 0; i < 4; i++) {
        float mm[4], li[4];
        #pragma unroll
        for (int r = 0; r < 4; r++) {
            int gr = it * 128 + mBase + i * 16 + quad * 4 + r;
            mm[r] = Mrow[(size_t)h * S + gr];
            li[r] = Li[(size_t)h * S + gr];
        }
        #pragma unroll
        for (int j = 0; j < 4; j++)
            #pragma unroll
            for (int r = 0; r < 4; r++) {
                int lr = mBase + i * 16 + quad * 4 + r;
                int lc = nBase + j * 16 + col;
                float v = (diag && lc > lr) ? 0.f
                          : __expf(acc[i][j][r] - mm[r]) * li[r];
                Pt[(size_t)lr * S + lc] = v;
            }
    }
}

// ---------------- small prep kernels ----------------
// fp32 in[R][C] (row stride inLd) -> bf16 out[C][R] (packed)
__global__ __launch_bounds__(256) void transpose_cvt(const float* __restrict__ in,
                                                     unsigned short* __restrict__ out,
                                                     int R, int C, int inLd)
{
    __shared__ float t[32][33];
    int r0 = blockIdx.y * 32, c0 = blockIdx.x * 32;
    int tid = threadIdx.x;
    int rr = tid >> 3, cc = (tid & 7) * 4;
    float4 v = *(const float4*)(in + (size_t)(r0 + rr) * inLd + c0 + cc);
    t[rr][cc] = v.x; t[rr][cc + 1] = v.y; t[rr][cc + 2] = v.z; t[rr][cc + 3] = v.w;
    __syncthreads();
    int oc = tid >> 3, orr = (tid & 7) * 4;
    ushort4 o;
    o.x = f2bf(t[orr][oc]);     o.y = f2bf(t[orr + 1][oc]);
    o.z = f2bf(t[orr + 2][oc]); o.w = f2bf(t[orr + 3][oc]);
    *(ushort4*)(out + (size_t)(c0 + oc) * R + r0 + orr) = o;
}

// fp32 -> bf16 flat convert (8 elems/thread)
__global__ __launch_bounds__(256) void cvt_bf16(const float* __restrict__ in,
                                                unsigned short* __restrict__ out, int n)
{
    int i = (blockIdx.x * 256 + threadIdx.x) * 8;
    if (i >= n) return;
    float4 a = *(const float4*)(in + i);
    float4 b = *(const float4*)(in + i + 4);
    unsigned int w0 = (unsigned int)f2bf(a.x) | ((unsigned int)f2bf(a.y) << 16);
    unsigned int w1 = (unsigned int)f2bf(a.z) | ((unsigned int)f2bf(a.w) << 16);
    unsigned int w2 = (unsigned int)f2bf(b.x) | ((unsigned int)f2bf(b.y) << 16);
    unsigned int w3 = (unsigned int)f2bf(b.z) | ((unsigned int)f2bf(b.w) << 16);
    *(uint4*)(out + i) = make_uint4(w0, w1, w2, w3);
}

extern "C" void kernel_launch(void* const* d_in, const int* in_sizes, int n_in,
                              void* d_out, int out_size, void* d_ws, size_t ws_size,
                              hipStream_t stream)
{
    const float* x    = (const float*)d_in[0];
    // d_in[1] = mask: causal triu(k=1), implemented analytically — unused.
    const float* cosp = (const float*)d_in[2];
    const float* sinp = (const float*)d_in[3];
    const float* Wq   = (const float*)d_in[4];
    const float* Wk   = (const float*)d_in[5];
    const float* Wv   = (const float*)d_in[6];
    const float* Wout = (const float*)d_in[7];

    float* out0 = (float*)d_out;               // (S, E) fp32
    float* Pout = out0 + (size_t)S * E;        // (NH, S, S) fp32

    // Workspace layout (~48.3 MB of 64 MiB, no aliasing)
    unsigned short* Wqkvt = (unsigned short*)d_ws;         // [3072][2048] bf16 (Wq^T|Wk^T|Wv^T)
    unsigned short* Woutt = Wqkvt + (size_t)3072 * E;      // [2048][2048] bf16 Wout^T
    unsigned short* xbf   = Woutt + (size_t)E * E;         // [2048][2048] bf16 x
    unsigned short* Qbf   = xbf   + (size_t)S * E;         // [2048][2048] bf16 roped+scaled Q
    unsigned short* Kbf   = Qbf   + (size_t)S * E;         // [2048][512]  bf16 roped K
    unsigned short* Vt    = Kbf   + (size_t)S * (NG * HD); // [512][2048]  bf16 V^T
    unsigned short* Obf   = Vt    + (size_t)(NG * HD) * S; // [2048][2048] bf16 attn out
    float* Mrow = (float*)(Obf + (size_t)S * E);           // [NH][S] row max
    float* Li   = Mrow + (size_t)NH * S;                   // [NH][S] 1/row-sum

    dim3 blk(256);
    // Weight transposes into concatenated QKV^T + Wout^T; x -> bf16
    transpose_cvt<<<dim3(E / 32, E / 32), blk, 0, stream>>>(Wq, Wqkvt, E, E, E);
    transpose_cvt<<<dim3((NG * HD) / 32, E / 32), blk, 0, stream>>>(Wk, Wqkvt + (size_t)E * E, E, NG * HD, NG * HD);
    transpose_cvt<<<dim3((NG * HD) / 32, E / 32), blk, 0, stream>>>(Wv, Wqkvt + (size_t)(E + NG * HD) * E, E, NG * HD, NG * HD);
    transpose_cvt<<<dim3(E / 32, E / 32), blk, 0, stream>>>(Wout, Woutt, E, E, E);
    cvt_bf16<<<dim3((S * E) / (256 * 8)), blk, 0, stream>>>(x, xbf, S * E);

    // Fused QKV projection + RoPE/scale/V-transpose epilogue (bf16 outputs direct)
    qkv_gemm_fused<<<dim3(3072 / 128, S / 128), blk, 0, stream>>>(xbf, Wqkvt, cosp, sinp, Qbf, Kbf, Vt);

    // Single-pass flash: O + per-row (m, 1/l)
    attn_flash<<<dim3(NH, S / 64), blk, 0, stream>>>(Qbf, Kbf, Vt, Obf, Mrow, Li);

    // P-writer: recompute S once, exp-normalize, write final P (incl. zeros)
    p_write<<<dim3(S / 128, S / 128, NH), blk, 0, stream>>>(Qbf, Kbf, Mrow, Li, Pout);

    // Output projection
    gemm_mfma_as<false><<<dim3(E / 128, S / 128), blk, 0, stream>>>(Obf, E, Woutt, E, out0, E, E);
}

// Round 9
// 489.148 us; speedup vs baseline: 1.0448x; 1.0448x over previous
//
#include <hip/hip_runtime.h>
#include <stdint.h>

#define S 2048
#define E 2048
#define NH 16
#define NG 4
#define HD 128
#define BK 64      // K-step for the async global_load_lds GEMM core

using short8 = __attribute__((ext_vector_type(8))) short;  // 8 bf16 (4 VGPRs)
using f32x4  = __attribute__((ext_vector_type(4))) float;  // 4 fp32 acc

__device__ __forceinline__ unsigned short f2bf(float f){
    union { float f; unsigned int i; } v; v.f = f;
    unsigned int x = v.i;
    unsigned int r = x + 0x7FFFu + ((x >> 16) & 1u);  // round-to-nearest-even
    return (unsigned short)(r >> 16);
}

// ---------------- async (global_load_lds) helpers ----------------
__device__ __forceinline__ void async_cp16(const unsigned short* g, unsigned short* l){
    __builtin_amdgcn_global_load_lds((const __attribute__((address_space(1))) void*)g,
                                     (__attribute__((address_space(3))) void*)l,
                                     16, 0, 0);
}

// Stage a 128 x BK(=64) bf16 tile, linear LDS dest, XOR-swizzled source chunks.
__device__ __forceinline__ void stage_tile_async(const unsigned short* __restrict__ G,
                                                 int ld, int k0,
                                                 unsigned short* lds)
{
    int tid = threadIdx.x;
    #pragma unroll
    for (int c = 0; c < 4; c++) {
        int e  = (c * 256 + tid) * 8;   // dest elem index in tile (0..8191)
        int r  = e >> 6;                // row 0..127
        int cl = (e >> 3) & 7;          // dest 16B chunk 0..7
        int sc = cl ^ (r & 7);          // swizzled source chunk
        async_cp16(G + (size_t)r * ld + k0 + sc * 8, lds + e);
    }
}

// Stage a 128 x 128 bf16 tile (32 KB): 16 chunks/row, XOR-swizzle with row&15.
__device__ __forceinline__ void stage_128x128(const unsigned short* __restrict__ G,
                                              int ld, unsigned short* lds)
{
    int tid = threadIdx.x;
    #pragma unroll
    for (int c = 0; c < 8; c++) {
        int e  = (c * 256 + tid) * 8;   // 0..16383
        int r  = e >> 7;                // row 0..127
        int cl = (e >> 3) & 15;         // dest chunk 0..15
        int sc = cl ^ (r & 15);         // swizzled source chunk
        async_cp16(G + (size_t)r * ld + sc * 8, lds + e);
    }
}

// Stage a 64 x 128 bf16 tile (16 KB).
__device__ __forceinline__ void stage_64x128(const unsigned short* __restrict__ G,
                                             int ld, unsigned short* lds)
{
    int tid = threadIdx.x;
    #pragma unroll
    for (int c = 0; c < 4; c++) {
        int e  = (c * 256 + tid) * 8;   // 0..8191
        int r  = e >> 7;                // row 0..63
        int cl = (e >> 3) & 15;
        int sc = cl ^ (r & 15);
        async_cp16(G + (size_t)r * ld + sc * 8, lds + e);
    }
}

// ---------------- bf16 GEMM core: 128x128 tile, BK=64, LDS double-buffered
// T3-minimum 2-phase: issue next tile's global_load_lds BEFORE computing the
// current one; one __syncthreads() per K-step (drains vmcnt for the prefetch
// and guards the buffer swap).
__device__ __forceinline__ void gemm_core_async(const unsigned short* __restrict__ A, int lda,
                                                const unsigned short* __restrict__ Bt, int ldb,
                                                int K, f32x4 acc[4][4],
                                                unsigned short* lA, unsigned short* lB) // each [2][128*BK]
{
    int tid = threadIdx.x;
    int wave = tid >> 6, lane = tid & 63;
    int mBase = (wave >> 1) * 64, nBase = (wave & 1) * 64;
    int rowA = lane & 15, qc = lane >> 4;
    int nt = K / BK;
    stage_tile_async(A,  lda, 0, lA);
    stage_tile_async(Bt, ldb, 0, lB);
    __syncthreads();
    int cur = 0;
    for (int t = 0; t < nt; ++t) {
        if (t + 1 < nt) {   // prefetch next K-step into the other buffer
            stage_tile_async(A,  lda, (t + 1) * BK, lA + (cur ^ 1) * (128 * BK));
            stage_tile_async(Bt, ldb, (t + 1) * BK, lB + (cur ^ 1) * (128 * BK));
        }
        const unsigned short* cA = lA + cur * (128 * BK);
        const unsigned short* cB = lB + cur * (128 * BK);
        #pragma unroll
        for (int s = 0; s < 2; s++) {
            short8 af[4], bfr[4];
            #pragma unroll
            for (int i = 0; i < 4; i++) {
                int r  = mBase + i * 16 + rowA;
                int ch = (s * 4 + qc) ^ (r & 7);
                af[i] = *(const short8*)&cA[r * BK + ch * 8];
            }
            #pragma unroll
            for (int j = 0; j < 4; j++) {
                int r  = nBase + j * 16 + rowA;
                int ch = (s * 4 + qc) ^ (r & 7);
                bfr[j] = *(const short8*)&cB[r * BK + ch * 8];
            }
            #pragma unroll
            for (int i = 0; i < 4; i++)
                #pragma unroll
                for (int j = 0; j < 4; j++)
                    acc[i][j] = __builtin_amdgcn_mfma_f32_16x16x32_bf16(af[i], bfr[j], acc[i][j], 0, 0, 0);
        }
        __syncthreads();   // prefetch landed + all waves done with cur
        cur ^= 1;
    }
}

// C/D layout: col = lane&15, row = (lane>>4)*4 + reg.
template<bool BF16OUT>
__device__ __forceinline__ void epilogue(f32x4 acc[4][4], void* Cv, int ldc,
                                         int row0, int col0, float scale)
{
    int tid = threadIdx.x, wave = tid >> 6, lane = tid & 63;
    int mBase = (wave >> 1) * 64, nBase = (wave & 1) * 64;
    int col = lane & 15, quad = lane >> 4;
    #pragma unroll
    for (int i = 0; i < 4; i++)
        #pragma unroll
        for (int j = 0; j < 4; j++)
            #pragma unroll
            for (int r = 0; r < 4; r++) {
                int gr = row0 + mBase + i * 16 + quad * 4 + r;
                int gc = col0 + nBase + j * 16 + col;
                float v = acc[i][j][r] * scale;
                if (BF16OUT) ((unsigned short*)Cv)[(size_t)gr * ldc + gc] = f2bf(v);
                else         ((float*)Cv)[(size_t)gr * ldc + gc] = v;
            }
}

template<bool BF16OUT>
__global__ __launch_bounds__(256) void gemm_mfma_as(const unsigned short* __restrict__ A, int lda,
                                                    const unsigned short* __restrict__ Bt, int ldb,
                                                    void* __restrict__ C, int ldc, int K)
{
    __shared__ unsigned short lA[2 * 128 * BK];
    __shared__ unsigned short lB[2 * 128 * BK];
    int row0 = blockIdx.y * 128, col0 = blockIdx.x * 128;
    f32x4 acc[4][4] = {};
    gemm_core_async(A + (size_t)row0 * lda, lda, Bt + (size_t)col0 * ldb, ldb, K, acc, lA, lB);
    epilogue<BF16OUT>(acc, C, ldc, row0, col0, 1.0f);
}

// ---------------- single-pass flash attention ----------------
// Each WAVE owns complete rows (16 q-rows x all 128 cols) -> softmax stats
// are wave-local. Online rescale of the O accumulator; emits per-row (m, 1/l)
// for the P-writer kernel.
__device__ __forceinline__ float rmax16(float v){
    v = fmaxf(v, __shfl_xor(v, 1)); v = fmaxf(v, __shfl_xor(v, 2));
    v = fmaxf(v, __shfl_xor(v, 4)); v = fmaxf(v, __shfl_xor(v, 8));
    return v;
}
__device__ __forceinline__ float rsum16(float v){
    v += __shfl_xor(v, 1); v += __shfl_xor(v, 2);
    v += __shfl_xor(v, 4); v += __shfl_xor(v, 8);
    return v;
}

// QK^T: 16 rows (this wave) x 128 cols from Q-frags (regs) + K tile in LDS.
__device__ __forceinline__ void qk_compute(const short8 qf[4], const unsigned short* lK,
                                           int rowA, int quad, f32x4 sacc[8])
{
    #pragma unroll
    for (int j = 0; j < 8; j++)
        #pragma unroll
        for (int r = 0; r < 4; r++) sacc[j][r] = 0.f;
    #pragma unroll
    for (int ks = 0; ks < 4; ks++) {
        int ch = (ks * 4 + quad) ^ rowA;   // (j*16+rowA)&15 == rowA
        #pragma unroll
        for (int j = 0; j < 8; j++) {
            short8 kf = *(const short8*)&lK[(j * 16 + rowA) * 128 + ch * 8];
            sacc[j] = __builtin_amdgcn_mfma_f32_16x16x32_bf16(qf[ks], kf, sacc[j], 0, 0, 0);
        }
    }
}

__global__ __launch_bounds__(256, 2) void attn_flash(const unsigned short* __restrict__ Q,
                                                     const unsigned short* __restrict__ Kb,
                                                     const unsigned short* __restrict__ Vt,
                                                     unsigned short* __restrict__ Obf,
                                                     float* __restrict__ Mrow,
                                                     float* __restrict__ Li)
{
    __shared__ unsigned short lK[128 * 128];   // K tile (front 16KB doubles as Q tile)
    __shared__ unsigned short lV[128 * 128];   // V^T tile
    __shared__ unsigned short lP[64 * 128];    // packed bf16 unnormalized P tile
    int h = blockIdx.x, qt = (gridDim.y - 1) - blockIdx.y, g = h >> 2; // heavy blocks first
    int jtm = qt >> 1;                 // diag (last) K/V tile index
    int rbase = (qt & 1) * 64;         // our rows' offset within the 128-row diag tile
    int tid = threadIdx.x, wave = tid >> 6, lane = tid & 63;
    int rowA = lane & 15, quad = lane >> 4;

    // Q (64x128, pre-scaled by 1/sqrt(HD)) -> LDS -> registers
    stage_64x128(Q + (size_t)(qt * 64) * (NH * HD) + h * HD, NH * HD, lK);
    __syncthreads();
    short8 qf[4];
    #pragma unroll
    for (int ks = 0; ks < 4; ks++) {
        int r = wave * 16 + rowA;
        int ch = (ks * 4 + quad) ^ rowA;   // r&15 == rowA
        qf[ks] = *(const short8*)&lK[r * 128 + ch * 8];
    }

    f32x4 m_, l_;
    #pragma unroll
    for (int r = 0; r < 4; r++) { m_[r] = -1e30f; l_[r] = 0.f; }
    f32x4 oacc[8];
    #pragma unroll
    for (int j = 0; j < 8; j++)
        #pragma unroll
        for (int r = 0; r < 4; r++) oacc[j][r] = 0.f;

    for (int jt = 0; jt <= jtm; ++jt) {
        __syncthreads();   // prev round's lK/lV/lP fully consumed (also guards qf reads)
        stage_128x128(Kb + (size_t)(jt * 128) * (NG * HD) + g * HD, NG * HD, lK);
        stage_128x128(Vt + (size_t)(g * HD) * S + jt * 128, S, lV);
        __syncthreads();   // tiles resident
        f32x4 sacc[8];
        qk_compute(qf, lK, rowA, quad, sacc);
        if (jt == jtm) {
            #pragma unroll
            for (int j = 0; j < 8; j++)
                #pragma unroll
                for (int r = 0; r < 4; r++) {
                    int row = rbase + wave * 16 + quad * 4 + r;
                    int col = j * 16 + rowA;
                    if (col > row) sacc[j][r] = -1e30f;
                }
        }
        // online softmax update + O rescale; sacc becomes p = exp(s - m_new)
        #pragma unroll
        for (int r = 0; r < 4; r++) {
            float tm = sacc[0][r];
            #pragma unroll
            for (int j = 1; j < 8; j++) tm = fmaxf(tm, sacc[j][r]);
            tm = rmax16(tm);
            float mn = fmaxf(m_[r], tm);
            float sc = __expf(m_[r] - mn);
            float es = 0.f;
            #pragma unroll
            for (int j = 0; j < 8; j++) {
                float p = __expf(sacc[j][r] - mn);
                sacc[j][r] = p;
                es += p;
            }
            es = rsum16(es);
            l_[r] = l_[r] * sc + es;
            m_[r] = mn;
            #pragma unroll
            for (int j = 0; j < 8; j++) oacc[j][r] *= sc;
        }
        // pack unnormalized p -> lP (bf16, swizzled)
        #pragma unroll
        for (int j = 0; j < 8; j++)
            #pragma unroll
            for (int r = 0; r < 4; r++) {
                int row = wave * 16 + quad * 4 + r;    // local 0..63
                int col = j * 16 + rowA;
                int ch = col >> 3;
                lP[row * 128 + (((ch ^ (row & 15)) << 3) | (col & 7))] = f2bf(sacc[j][r]);
            }
        __syncthreads();   // lP fully packed
        #pragma unroll
        for (int ks = 0; ks < 4; ks++) {
            int ch = (ks * 4 + quad) ^ rowA;
            short8 pa = *(const short8*)&lP[(wave * 16 + rowA) * 128 + ch * 8];
            #pragma unroll
            for (int j = 0; j < 8; j++) {
                short8 vb = *(const short8*)&lV[(j * 16 + rowA) * 128 + ch * 8];
                oacc[j] = __builtin_amdgcn_mfma_f32_16x16x32_bf16(pa, vb, oacc[j], 0, 0, 0);
            }
        }
    }

    f32x4 linv;
    #pragma unroll
    for (int r = 0; r < 4; r++) linv[r] = 1.0f / l_[r];

    // O rows -> Obf (bf16, head-sliced cols), normalized
    #pragma unroll
    for (int j = 0; j < 8; j++)
        #pragma unroll
        for (int r = 0; r < 4; r++) {
            int row = qt * 64 + wave * 16 + quad * 4 + r;
            int col = h * HD + j * 16 + rowA;
            Obf[(size_t)row * (NH * HD) + col] = f2bf(oacc[j][r] * linv[r]);
        }

    // per-row softmax stats for the P-writer (one lane per row group)
    if (rowA == 0) {
        int grow0 = qt * 64 + wave * 16 + quad * 4;
        #pragma unroll
        for (int r = 0; r < 4; r++) {
            Mrow[(size_t)h * S + grow0 + r] = m_[r];
            Li[(size_t)h * S + grow0 + r]  = linv[r];
        }
    }
}

// ---------------- P-writer: recompute S once, write final P ----------------
__global__ __launch_bounds__(256) void p_write(const unsigned short* __restrict__ Q,
                                               const unsigned short* __restrict__ Kb,
                                               const float* __restrict__ Mrow,
                                               const float* __restrict__ Li,
                                               float* __restrict__ P)
{
    int jt = blockIdx.x, it = blockIdx.y, h = blockIdx.z;
    float* Pt = P + (size_t)h * S * S + (size_t)(it * 128) * S + jt * 128;
    int tid = threadIdx.x;
    if (jt > it) {   // upper triangle: zeros
        #pragma unroll
        for (int q = 0; q < 16; q++) {
            int e4 = q * 256 + tid;          // float4 index 0..4095
            int r  = e4 >> 5;                // 32 float4 per 128-col row
            int c4 = (e4 & 31) * 4;
            *(float4*)(Pt + (size_t)r * S + c4) = make_float4(0.f, 0.f, 0.f, 0.f);
        }
        return;
    }
    __shared__ unsigned short lA[2 * 128 * BK];
    __shared__ unsigned short lB[2 * 128 * BK];
    f32x4 acc[4][4] = {};
    gemm_core_async(Q + (size_t)(it * 128) * (NH * HD) + h * HD, NH * HD,
                    Kb + (size_t)(jt * 128) * (NG * HD) + (h >> 2) * HD, NG * HD,
                    HD, acc, lA, lB);
    // epilogue: exp(s - m) * linv, diag-masked
    int wave = tid >> 6, lane = tid & 63;
    int mBase = (wave >> 1) * 64, nBase = (wave & 1) * 64;
    int col = lane & 15, quad = lane >> 4;
    bool diag = (jt == it);
    #pragma unroll
    for (int i = 0; i < 4; i++) {
        float mm[4], li[4];
        #pragma unroll
        for (int r = 0; r < 4; r++) {
            int gr = it * 128 + mBase + i * 16 + quad * 4 + r;
            mm[r] = Mrow[(size_t)h * S + gr];
            li[r] = Li[(size_t)h * S + gr];
        }
        #pragma unroll
        for (int j = 0; j < 4; j++)
            #pragma unroll
            for (int r = 0; r < 4; r++) {
                int lr = mBase + i * 16 + quad * 4 + r;
                int lc = nBase + j * 16 + col;
                float v = (diag && lc > lr) ? 0.f
                          : __expf(acc[i][j][r] - mm[r]) * li[r];
                Pt[(size_t)lr * S + lc] = v;
            }
    }
}

// ---------------- small prep kernels ----------------
// fp32 in[R][C] (row stride inLd) -> bf16 out[C][R] (packed)
__global__ __launch_bounds__(256) void transpose_cvt(const float* __restrict__ in,
                                                     unsigned short* __restrict__ out,
                                                     int R, int C, int inLd)
{
    __shared__ float t[32][33];
    int r0 = blockIdx.y * 32, c0 = blockIdx.x * 32;
    int tid = threadIdx.x;
    int rr = tid >> 3, cc = (tid & 7) * 4;
    float4 v = *(const float4*)(in + (size_t)(r0 + rr) * inLd + c0 + cc);
    t[rr][cc] = v.x; t[rr][cc + 1] = v.y; t[rr][cc + 2] = v.z; t[rr][cc + 3] = v.w;
    __syncthreads();
    int oc = tid >> 3, orr = (tid & 7) * 4;
    ushort4 o;
    o.x = f2bf(t[orr][oc]);     o.y = f2bf(t[orr + 1][oc]);
    o.z = f2bf(t[orr + 2][oc]); o.w = f2bf(t[orr + 3][oc]);
    *(ushort4*)(out + (size_t)(c0 + oc) * R + r0 + orr) = o;
}

// fp32 -> bf16 flat convert (8 elems/thread)
__global__ __launch_bounds__(256) void cvt_bf16(const float* __restrict__ in,
                                                unsigned short* __restrict__ out, int n)
{
    int i = (blockIdx.x * 256 + threadIdx.x) * 8;
    if (i >= n) return;
    float4 a = *(const float4*)(in + i);
    float4 b = *(const float4*)(in + i + 4);
    unsigned int w0 = (unsigned int)f2bf(a.x) | ((unsigned int)f2bf(a.y) << 16);
    unsigned int w1 = (unsigned int)f2bf(a.z) | ((unsigned int)f2bf(a.w) << 16);
    unsigned int w2 = (unsigned int)f2bf(b.x) | ((unsigned int)f2bf(b.y) << 16);
    unsigned int w3 = (unsigned int)f2bf(b.z) | ((unsigned int)f2bf(b.w) << 16);
    *(uint4*)(out + i) = make_uint4(w0, w1, w2, w3);
}

// RoPE fp32 (strided input) -> bf16 (packed output), optional scale fold.
__global__ void rope_bf16(const float* __restrict__ T, unsigned short* __restrict__ Tb,
                          const float* __restrict__ cosp, const float* __restrict__ sinp,
                          int nHeads, int inLd, int inOff, int outLd, float scale, int total)
{
    int idx = blockIdx.x * blockDim.x + threadIdx.x;
    if (idx >= total) return;
    int d = idx & 63;
    int head = (idx >> 6) % nHeads;
    int s = idx / (nHeads * 64);
    float c  = cosp[s * HD + d];
    float sn = sinp[s * HD + d];
    const float* ib = T + (size_t)s * inLd + inOff + head * HD + d;
    float x1 = ib[0], x2 = ib[64];
    unsigned short* ob = Tb + (size_t)s * outLd + head * HD + d;
    ob[0]  = f2bf((x1 * c - x2 * sn) * scale);
    ob[64] = f2bf((x2 * c + x1 * sn) * scale);
}

extern "C" void kernel_launch(void* const* d_in, const int* in_sizes, int n_in,
                              void* d_out, int out_size, void* d_ws, size_t ws_size,
                              hipStream_t stream)
{
    const float* x    = (const float*)d_in[0];
    // d_in[1] = mask: causal triu(k=1), implemented analytically — unused.
    const float* cosp = (const float*)d_in[2];
    const float* sinp = (const float*)d_in[3];
    const float* Wq   = (const float*)d_in[4];
    const float* Wk   = (const float*)d_in[5];
    const float* Wv   = (const float*)d_in[6];
    const float* Wout = (const float*)d_in[7];

    float* out0 = (float*)d_out;               // (S, E) fp32
    float* Pout = out0 + (size_t)S * E;        // (NH, S, S) fp32

    // Workspace layout (~59 MB of 64 MiB)
    unsigned short* Wqkvt = (unsigned short*)d_ws;         // [3072][2048] bf16 (Wq^T|Wk^T|Wv^T)
    unsigned short* Qbf   = Wqkvt + (size_t)3072 * E;      // [2048][2048] bf16 roped+scaled Q
    unsigned short* Kbf   = Qbf   + (size_t)S * E;         // [2048][512]  bf16 roped K
    unsigned short* Vt    = Kbf   + (size_t)S * (NG * HD); // [512][2048]  bf16 V^T
    unsigned short* Obf   = Vt    + (size_t)(NG * HD) * S; // [2048][2048] bf16 attn out
    float* QKVb = (float*)(Obf + (size_t)S * E);           // [2048][3072] fp32 QKV proj
    float* Mrow = QKVb + (size_t)S * 3072;                 // [NH][S] row max
    float* Li   = Mrow + (size_t)NH * S;                   // [NH][S] 1/row-sum
    // Aliases (disjoint lifetimes):
    unsigned short* xbf   = Obf;                           // x bf16: dies before Obf born
    unsigned short* Woutt = (unsigned short*)QKVb;         // Wout^T: born after QKVb dies

    dim3 blk(256);
    // Weight transposes into concatenated QKV^T, x -> bf16
    transpose_cvt<<<dim3(E / 32, E / 32), blk, 0, stream>>>(Wq, Wqkvt, E, E, E);
    transpose_cvt<<<dim3((NG * HD) / 32, E / 32), blk, 0, stream>>>(Wk, Wqkvt + (size_t)E * E, E, NG * HD, NG * HD);
    transpose_cvt<<<dim3((NG * HD) / 32, E / 32), blk, 0, stream>>>(Wv, Wqkvt + (size_t)(E + NG * HD) * E, E, NG * HD, NG * HD);
    cvt_bf16<<<dim3((S * E) / (256 * 8)), blk, 0, stream>>>(x, xbf, S * E);

    // Fused QKV projection: [2048 x 2048] x [2048 x 3072] -> QKVb fp32 (ldc=3072)
    gemm_mfma_as<false><<<dim3(3072 / 128, S / 128), blk, 0, stream>>>(xbf, E, Wqkvt, E, QKVb, 3072, E);

    // RoPE: Q (1/sqrt(HD) folded), K; V transpose
    rope_bf16<<<(S * NH * 64 + 255) / 256, blk, 0, stream>>>(QKVb, Qbf, cosp, sinp, NH, 3072, 0, NH * HD,
                                                             0.08838834764831845f, S * NH * 64);
    rope_bf16<<<(S * NG * 64 + 255) / 256, blk, 0, stream>>>(QKVb, Kbf, cosp, sinp, NG, 3072, E, NG * HD,
                                                             1.0f, S * NG * 64);
    transpose_cvt<<<dim3((NG * HD) / 32, S / 32), blk, 0, stream>>>(QKVb + E + NG * HD, Vt, S, NG * HD, 3072);

    // Wout^T (aliases QKVb region — QKVb dead now; Mrow/Li live outside it)
    transpose_cvt<<<dim3(E / 32, E / 32), blk, 0, stream>>>(Wout, Woutt, E, E, E);

    // Single-pass flash: O + per-row (m, 1/l)
    attn_flash<<<dim3(NH, S / 64), blk, 0, stream>>>(Qbf, Kbf, Vt, Obf, Mrow, Li);

    // P-writer: recompute S once, exp-normalize, write final P (incl. zeros)
    p_write<<<dim3(S / 128, S / 128, NH), blk, 0, stream>>>(Qbf, Kbf, Mrow, Li, Pout);

    // Output projection
    gemm_mfma_as<false><<<dim3(E / 128, S / 128), blk, 0, stream>>>(Obf, E, Woutt, E, out0, E, E);
}